// Round 14
// baseline (210.740 us; speedup 1.0000x reference)
//
#include <hip/hip_runtime.h>
#include <hip/hip_bf16.h>

// B=16, T=512, E=256, A=8. Inputs f32 (+int32 mask), outputs f32:
//   d_out: [ output 16*512*256 | attn 128*512*512 ]
// R24: R23 (best, 209.7us) + micro-polish: (a) preps merged into one
// launch (branch on blockIdx.z==16; -1 dispatch gap); (b) k_attnpv af[8]
// frag loads hoisted above the msk barrier (global loads count vmcnt;
// barrier_lds drains lgkmcnt only -> loads fly across the barrier);
// (c) s_setprio(1) around Gram/PV MFMA clusters (T5: 2 independent
// blocks/CU at different phases -> scheduler role diversity).
// k_attnpv occupancy is VGPR-capped at 16 waves/CU (4 waves/SIMD x 4):
// z=4 variants refuted by arithmetic (2x Gram + halved PV batching, no
// occupancy gain). Structure: R23's 512-thread, z=2, all-4-softmax-first,
// kc-outer batched-4 PV, frag-major XwsF transport, Mt2xNt2 k_out.

#define Bt 16
#define Tt 512
#define Et 256
#define At 8

typedef __attribute__((ext_vector_type(8))) short short8;   // 8 x bf16
typedef __attribute__((ext_vector_type(4))) float floatx4;

static __device__ __forceinline__ unsigned short f2bf(float x) {
    union { float f; unsigned u; } v; v.f = x;
    unsigned r = v.u + 0x7fffu + ((v.u >> 16) & 1u);  // RNE
    return (unsigned short)(r >> 16);
}

static __device__ __forceinline__ floatx4 mfma16(short8 a, short8 b, floatx4 c) {
    return __builtin_amdgcn_mfma_f32_16x16x32_bf16(a, b, c, 0, 0, 0);
}

// Barrier that waits only on LDS ops (lgkmcnt), NOT on in-flight global
// loads/stores (vmcnt). All barriers in k_attnpv protect LDS-only data
// (S / Pb / Xb2 / msk), so lgkm-only is sufficient (audited R11/R12/R18).
static __device__ __forceinline__ void barrier_lds() {
    __builtin_amdgcn_sched_barrier(0);
    asm volatile("s_waitcnt lgkmcnt(0)" ::: "memory");
    __builtin_amdgcn_s_barrier();
    __builtin_amdgcn_sched_barrier(0);
}

// ---- merged prep: z<16 -> sentG/sentFB tiles; z==16 -> Wp ---------------
// sentG block (bb, st, ec): elem(l16,quad,j) = sent[bb][st*16+l16][ec*32+quad*8+j]
// sentFB block (bb, et, sc): elem(l16,quad,j) = sent[bb][sc*32+quad*8+j][et*16+l16]
// Wp block (nt, kc):         elem(l16,quad,j) = W[nt*16+l16][kc*32+quad*8+j]
__global__ __launch_bounds__(256) void k_prep(const float* __restrict__ sent,
                                              const float* __restrict__ W,
                                              unsigned short* __restrict__ sentG,
                                              unsigned short* __restrict__ sentFB,
                                              unsigned short* __restrict__ Wp) {
    if (blockIdx.z == 16) {
        // ---- Wp prep (verified R9), nt = blockIdx.x, pc = blockIdx.y ----
        int nt = blockIdx.x;              // 16
        int pc = blockIdx.y;              // 8 chunks of 2 p-iterations
        int wave = threadIdx.x >> 6, lane = threadIdx.x & 63,
            quad = lane >> 4, l16 = lane & 15;
        const int KK = At * Et;           // 2048
        for (int p = pc * 2; p < pc * 2 + 2; ++p) {
            int kc = wave + 4 * p;        // 64
            const float* src = W + (size_t)(nt * 16 + l16) * KK + kc * 32 + quad * 8;
            union { short8 s; unsigned short e[8]; } u;
#pragma unroll
            for (int j = 0; j < 8; ++j) u.e[j] = f2bf(src[j]);
            *(short8*)(Wp + (((size_t)nt * 64 + kc) << 9) + lane * 8) = u.s;
        }
        return;
    }
    int bb = blockIdx.z;
    int s0 = blockIdx.x * 32;       // 16
    int e0 = blockIdx.y * 32;       // 8
    __shared__ float tile[32][33];
    int c  = threadIdx.x & 31;
    int r4 = threadIdx.x >> 5;
    for (int i = 0; i < 4; ++i) {
        int r = r4 + 8 * i;
        tile[r][c] = sent[(bb * Tt + s0 + r) * Et + e0 + c];
    }
    __syncthreads();
    int wv = threadIdx.x >> 6, lane = threadIdx.x & 63, quad = lane >> 4, l16 = lane & 15;
    union { short8 s; unsigned short e[8]; } u;
    if (wv < 2) {
        // sentG block (bb, st = s0/16 + wv, ec = e0/32)
#pragma unroll
        for (int j = 0; j < 8; ++j) u.e[j] = f2bf(tile[wv * 16 + l16][quad * 8 + j]);
        *(short8*)(sentG + (((size_t)(bb * 32 + (s0 >> 4) + wv)) * 8 + (e0 >> 5)) * 512
                   + lane * 8) = u.s;
    } else {
        int h = wv - 2;
        // sentFB block (bb, et = e0/16 + h, sc = s0/32)
#pragma unroll
        for (int j = 0; j < 8; ++j) u.e[j] = f2bf(tile[quad * 8 + j][h * 16 + l16]);
        *(short8*)(sentFB + (((size_t)(bb * 16 + (e0 >> 4) + h)) * 16 + (s0 >> 5)) * 512
                   + lane * 8) = u.s;
    }
}

// ---- fused: Gram + 4x softmax + batched PV + frag-major X out ------------
// 512 THREADS (8 waves). 1D grid, 1024 blocks. bb-major XCD-chunked swizzle:
// XCD k owns bb {2k,2k+1}. Per block: 4 attrs (z*4..+4), R18 phase order.
__global__ __launch_bounds__(512) void k_attnpv(const unsigned short* __restrict__ sentG,
                                                const unsigned short* __restrict__ sentFB,
                                                const int* __restrict__ mask,
                                                const float* __restrict__ atr,
                                                float* __restrict__ attnf,
                                                unsigned short* __restrict__ XwsF) {
    int hw = blockIdx.x;                        // 1024, 1024%8==0 -> bijective
    int logical = (hw & 7) * 128 + (hw >> 3);
    int bb = logical >> 6;                      // 16 (slow axis: 2 per XCD)
    int z  = (logical >> 5) & 1;                // a-group 0/1
    int t0 = (logical & 31) * 16;               // 32 tiles
    int a0 = z * 4;

    // 64 KB region: phase A = S[16][516] scores; phase B = Pb[4][8192] bf16;
    // phase C = Xb2[4][4096] bf16 (aliases Pb[0..1] after barrier).
    __shared__ __align__(16) float Sbuf[16384];
    __shared__ float msk[512];
    __shared__ float mrowv[16];
    unsigned short* Pb  = (unsigned short*)Sbuf;
    unsigned short* Xb2 = (unsigned short*)Sbuf;

    int tid = threadIdx.x;
    int wv = tid >> 6, lane = tid & 63, quad = lane >> 4, l16 = lane & 15;

    // af[8] loads issued BEFORE the msk barrier: global loads count vmcnt,
    // barrier_lds drains lgkmcnt only -> these fly across the barrier and
    // land before the Gram MFMAs consume them.
    const unsigned short* Gbase = sentG + ((size_t)(bb * 32 + (t0 >> 4)) * 8) * 512 + lane * 8;
    short8 af[8];
#pragma unroll
    for (int kk = 0; kk < 8; ++kk) af[kk] = *(const short8*)(Gbase + kk * 512);

    msk[tid] = (mask[bb * Tt + tid] != 0) ? 1.0f : 0.0f;
    if (tid < 16) mrowv[tid] = (mask[bb * Tt + t0 + tid] != 0) ? 1.0f : 0.0f;
    barrier_lds();

    // ---- Gram: A and B frags both from frag-major sentG (contiguous 1KB/wave)
    // 8 waves x 4 nt-tiles each = 32 nt-tiles.
    __builtin_amdgcn_s_setprio(1);
#pragma unroll
    for (int i = 0; i < 4; ++i) {
        int nt = wv * 4 + i;
        const unsigned short* Bb = sentG + ((size_t)(bb * 32 + nt) * 8) * 512 + lane * 8;
        floatx4 c = {0.f, 0.f, 0.f, 0.f};
#pragma unroll
        for (int kk = 0; kk < 8; ++kk)
            c = mfma16(af[kk], *(const short8*)(Bb + kk * 512), c);
#pragma unroll
        for (int r = 0; r < 4; ++r) {
            int cidx = nt * 16 + l16;
            Sbuf[(quad * 4 + r) * 516 + cidx] = c[r] * msk[cidx] * mrowv[quad * 4 + r];
        }
    }
    __builtin_amdgcn_s_setprio(0);
    barrier_lds();

    // ---- hoist masked scores to regs; one max-reduction for all attrs.
    // 512 thr: row = tid>>5 (16 rows), cl = tid&31, 16 elems/thread.
    int row = tid >> 5, cl = tid & 31;
    float w[16];
    float wmax = -1e30f;
#pragma unroll
    for (int i4 = 0; i4 < 4; ++i4) {
        float4 v = *(const float4*)&Sbuf[row * 516 + i4 * 128 + cl * 4];
        w[i4 * 4 + 0] = v.x; w[i4 * 4 + 1] = v.y; w[i4 * 4 + 2] = v.z; w[i4 * 4 + 3] = v.w;
        wmax = fmaxf(wmax, fmaxf(fmaxf(v.x, v.y), fmaxf(v.z, v.w)));
    }
    // row group = 32 contiguous lanes, 32-aligned -> xor offsets 16..1 stay inside
#pragma unroll
    for (int off = 16; off >= 1; off >>= 1) wmax = fmaxf(wmax, __shfl_xor(wmax, off, 64));
    barrier_lds();    // all S reads done before Pb overwrites the region

    int L = (t0 >> 3) & 15;                 // t'-row base within its 16-tile

    // ---- phase 1: all 4 softmaxes -> attn stores + Pb[al] (one p[] live)
#pragma unroll
    for (int al = 0; al < 4; ++al) {
        int a = a0 + al;
        float av = atr[bb * At + a];
        float coef = av * av * (1.0f / 16.0f);
        float mx = coef * wmax;
        float p[16];
        float sum = 0.f;
#pragma unroll
        for (int j = 0; j < 16; ++j) {
            float e = __expf(fmaf(coef, w[j], -mx));
            p[j] = e;
            sum += e;
        }
#pragma unroll
        for (int off = 16; off >= 1; off >>= 1) sum += __shfl_xor(sum, off, 64);
        float inv = 1.0f / sum;
#pragma unroll
        for (int j = 0; j < 16; ++j) p[j] *= inv;

        // attn f32 store (coalesced) -- fire-and-forget; the lgkm-only
        // barriers below do NOT drain these.
        float* orow = attnf + ((size_t)(bb * At + a) * Tt + (t0 + row)) * Tt;
#pragma unroll
        for (int i4 = 0; i4 < 4; ++i4) {
            float4 v;
            v.x = p[i4 * 4 + 0]; v.y = p[i4 * 4 + 1];
            v.z = p[i4 * 4 + 2]; v.w = p[i4 * 4 + 3];
            *(float4*)(orow + i4 * 128 + cl * 4) = v;
        }

        // P -> Pb[al] bf16 in chunk-XOR A-frag layout.
        // col c = i4*128 + cl*4 + j -> h = i4*16 + (cl>>1), pos = (cl&1)*4 + j
#pragma unroll
        for (int i4 = 0; i4 < 4; ++i4) {
            unsigned b0 = __float_as_uint(p[i4 * 4 + 0]) + 0x8000u;
            unsigned b1 = __float_as_uint(p[i4 * 4 + 1]) + 0x8000u;
            unsigned b2 = __float_as_uint(p[i4 * 4 + 2]) + 0x8000u;
            unsigned b3 = __float_as_uint(p[i4 * 4 + 3]) + 0x8000u;
            uint2 pk;
            pk.x = __builtin_amdgcn_perm(b1, b0, 0x07060302u);
            pk.y = __builtin_amdgcn_perm(b3, b2, 0x07060302u);
            int h = i4 * 16 + (cl >> 1);
            *(uint2*)(Pb + al * 8192 + row * 512 + ((h ^ (row & 7)) << 3)
                      + (cl & 1) * 4) = pk;
        }
    }
    barrier_lds();   // all Pb visible before PV reads (LDS only)

    // ---- phase 2: batched PV -- 8 waves x 2 et-tiles; each bfr feeds 4 attrs
    floatx4 acc[4][2];
#pragma unroll
    for (int al = 0; al < 4; ++al)
#pragma unroll
        for (int i = 0; i < 2; ++i) acc[al][i] = (floatx4){0.f, 0.f, 0.f, 0.f};

    __builtin_amdgcn_s_setprio(1);
    for (int kc = 0; kc < 16; ++kc) {
        short8 bfr[2];
#pragma unroll
        for (int i = 0; i < 2; ++i)
            bfr[i] = *(const short8*)(sentFB +
                (((size_t)(bb * 16 + wv * 2 + i) * 16 + kc) << 9) + lane * 8);
#pragma unroll
        for (int al = 0; al < 4; ++al) {
            short8 afr = *(const short8*)(Pb + al * 8192 + l16 * 512 +
                (((kc * 4 + quad) ^ (l16 & 7)) << 3));
#pragma unroll
            for (int i = 0; i < 2; ++i)
                acc[al][i] = mfma16(afr, bfr[i], acc[al][i]);
        }
    }
    __builtin_amdgcn_s_setprio(0);
    barrier_lds();   // all PV Pb-reads drained before Xb2 overwrites region

    // ---- phase 3: epilogue x4 -- Xb2[al] frag layout (R17-verified):
    //   t' = a*64 + t0/8 + g, k' = (tl&7)*256 + e
#pragma unroll
    for (int al = 0; al < 4; ++al) {
        float av = atr[bb * At + a0 + al];
#pragma unroll
        for (int i = 0; i < 2; ++i) {
            int W16 = wv * 2 + i;                 // e / 16
            int kcb = W16 >> 1;
            int qp  = (W16 & 1) * 2 + (l16 >> 3);
            int jp  = l16 & 7;
#pragma unroll
            for (int r = 0; r < 4; ++r) {
                int tl = quad * 4 + r;
                Xb2[al * 4096 + (((tl & 7) * 8 + kcb) << 6) + qp * 16
                    + ((tl >> 3) << 3) + jp] = f2bf(av * acc[al][i][r]);
            }
        }
    }
    barrier_lds();   // Xb2 visible before copy reads (LDS only)

    // ---- Xb2 -> XwsF frag blocks (TPT = a*4 + t0/128), rows L, L+1.
    // 512 thr: kc = tid>>3 (0..63), q8 = tid&7 -> one short8 each per attr.
#pragma unroll
    for (int al = 0; al < 4; ++al) {
        int a = a0 + al;
        int kc = tid >> 3, q8 = tid & 7;
        int TPT = (a << 2) + (t0 >> 7);
        size_t base = (((size_t)(bb * 32 + TPT)) * 64 + kc) * 512;
        short8 v = *(const short8*)(Xb2 + al * 4096 + (kc << 6)
                                    + (q8 >> 1) * 16 + (q8 & 1) * 8);
        *(short8*)(XwsF + base + ((q8 >> 1) * 16 + L + (q8 & 1)) * 8) = v;
    }
}

// ---- K3: out = Xr @ W^T + bias. LDS-free streaming GEMM, Mt=2 x Nt=2 -----
// 512 blocks (16 bb x 16 TPT-pairs x 2 n-halves), bb-major XCD swizzle.
// Each wave: 2 TPT rows-tiles x 2 nt col-tiles; every A-frag and B-frag
// load feeds 2 MFMAs (loads/MFMA 1.0; L2 768->512MB). Per-output-element
// kc accumulation order unchanged -> bitwise-identical.
__global__ __launch_bounds__(256) void k_out(const unsigned short* __restrict__ XwsF,
                                             const unsigned short* __restrict__ Wp,
                                             const float* __restrict__ bias,
                                             float* __restrict__ out) {
    int hw = blockIdx.x;                    // 512, 512%8==0 -> bijective
    int logical = (hw & 7) * 64 + (hw >> 3);
    int bb   = logical >> 5;                // 16 (2 per XCD)
    int TPT0 = ((logical >> 1) & 15) * 2;   // 0,2,..,30
    int nh   = logical & 1;                 // n half
    int tid = threadIdx.x;
    int wv = tid >> 6, lane = tid & 63, quad = lane >> 4, l16 = lane & 15;

    const unsigned short* A0 = XwsF + ((size_t)(bb * 32 + TPT0)) * 64 * 512 + lane * 8;
    const unsigned short* A1 = A0 + 64 * 512;
    floatx4 oacc[2][2];
#pragma unroll
    for (int m = 0; m < 2; ++m)
#pragma unroll
        for (int i = 0; i < 2; ++i) oacc[m][i] = (floatx4){0.f, 0.f, 0.f, 0.f};
    int nt0 = nh * 8 + wv * 2;
#pragma unroll 4
    for (int kc = 0; kc < 64; ++kc) {
        short8 a0 = *(const short8*)(A0 + kc * 512);
        short8 a1 = *(const short8*)(A1 + kc * 512);
#pragma unroll
        for (int i = 0; i < 2; ++i) {
            short8 bf = *(const short8*)(Wp +
                (((size_t)(nt0 + i) * 64 + kc) << 9) + lane * 8);
            oacc[0][i] = mfma16(a0, bf, oacc[0][i]);
            oacc[1][i] = mfma16(a1, bf, oacc[1][i]);
        }
    }
#pragma unroll
    for (int m = 0; m < 2; ++m) {
#pragma unroll
        for (int i = 0; i < 2; ++i) {
            int n = (nt0 + i) * 16 + l16;
            float bv = bias[n];
#pragma unroll
            for (int r = 0; r < 4; ++r) {
                int tp = (TPT0 + m) * 16 + quad * 4 + r;
                out[((size_t)bb * Tt + tp) * Et + n] = oacc[m][i][r] + bv;
            }
        }
    }
}

extern "C" void kernel_launch(void* const* d_in, const int* in_sizes, int n_in,
                              void* d_out, int out_size, void* d_ws, size_t ws_size,
                              hipStream_t stream) {
    const float* sent = (const float*)d_in[0];   // f32 (B,T,E)
    const int*   mask = (const int*)d_in[1];     // int32 (B,T)
    const float* atr  = (const float*)d_in[2];   // f32 (B,A)
    const float* W    = (const float*)d_in[3];   // f32 (E, A*E)
    const float* bias = (const float*)d_in[4];   // f32 (E)

    float* out0  = (float*)d_out;                     // 2,097,152 f32
    float* attnf = out0 + (size_t)Bt * Tt * Et;       // 33,554,432 f32

    char* ws = (char*)d_ws;
    unsigned short* sentG  = (unsigned short*)(ws);             // 4 MB
    unsigned short* sentFB = (unsigned short*)(ws + 4194304);   // 4 MB
    unsigned short* Wp     = (unsigned short*)(ws + 8388608);   // 1 MB
    unsigned short* XwsF   = (unsigned short*)(ws + 9437184);   // 32 MB frag-major
    // total 42.99 MB (== R2/R9 proven-safe footprint)

    hipLaunchKernelGGL(k_prep, dim3(Tt / 32, Et / 32, Bt + 1), dim3(256), 0, stream,
                       sent, W, sentG, sentFB, Wp);
    hipLaunchKernelGGL(k_attnpv, dim3(1024), dim3(512), 0, stream,
                       sentG, sentFB, mask, atr, attnf, XwsF);
    hipLaunchKernelGGL(k_out, dim3(512), dim3(256), 0, stream,
                       XwsF, Wp, bias, out0);
}